// Round 7
// baseline (72.985 us; speedup 1.0000x reference)
//
#include <hip/hip_runtime.h>
#include <hip/hip_bf16.h>
#include <math.h>

// FGN layer, single fused kernel, R7:
//   res = (X @ W^T + bias) * g
//   g   = exp(-(sum_k x^2*s^2 - 2*x*c*s^2 + c^2*s^2)),  s = min(ic, 1e8)
// Block = 64m x 32n, 256 thr, grid 512 (2 blocks/CU), XCD swizzle kept.
// Changes vs R6: (1) c^2 s^2 stream removed from MFMA -> fp32 VALU partial
// during B staging + shfl reduce into sCz[32] (-25% B LDS traffic & MFMAs,
// exact fp32 constant); (2) TK=128 -> only 2 K-tiles, 4 barriers total
// (was 8); (3) tile-1 globals prefetched between stage-0 and compute-0 so
// cold-HBM latency overlaps compute. LDS 59.5 KB/block -> 2 blocks/CU.

typedef __attribute__((ext_vector_type(8))) short short8;
typedef __attribute__((ext_vector_type(4))) float floatx4;

#define MFMA __builtin_amdgcn_mfma_f32_16x16x32_bf16
#define INDIM 256
#define OUTD  1024
#define BD    1024
#define TM 64
#define TN 32
#define TK 128
#define KSTR 136   // ushort stride = 272 B row: 16B-aligned, 2-way bank alias (free)

__device__ __forceinline__ unsigned pkbf(float a, float b) {
    union { __hip_bfloat162 h; unsigned u; } v;
    v.h = __float22bfloat162_rn(make_float2(a, b));
    return v.u;
}

__global__ __launch_bounds__(256, 2)
void fgn_fused(const float* __restrict__ X, const float* __restrict__ W,
               const float* __restrict__ Bias, const float* __restrict__ C,
               const float* __restrict__ IC, float* __restrict__ Out)
{
    __shared__ __align__(16) unsigned short As [TM * KSTR];
    __shared__ __align__(16) unsigned short As2[TM * KSTR];
    __shared__ __align__(16) unsigned short Bw [TN * KSTR];
    __shared__ __align__(16) unsigned short Bg1[TN * KSTR];
    __shared__ __align__(16) unsigned short Bg2[TN * KSTR];
    __shared__ float sCz[TN];

    // XCD-aware swizzle (neutral but harmless; preserves per-XCD L2 locality)
    const int b    = blockIdx.x;          // 0..511
    const int xcd  = b & 7;
    const int i    = b >> 3;              // 0..63
    const int n0   = (xcd + 8 * (i & 3)) * TN;
    const int m0   = (i >> 2) * TM;

    const int t    = threadIdx.x;
    const int w    = t >> 6;              // wave id: owns m-rows w*16..+15
    const int lane = t & 63;
    const int r    = lane & 15;
    const int q    = lane >> 4;

    // staging coordinates
    const int arow = t >> 2;              // 0..63, A tile row
    const int ak   = (t & 3) << 5;        // 0,32,64,96 (32 k's / thread)
    const int brow = t >> 3;              // 0..31, B tile row
    const int bk   = (t & 7) << 4;        // 0..112 (16 k's / thread)

    float4 xa[8], wv[4], cv[4], iv[4];
    float czp = 0.f;

    auto loadT = [&](int k0) {
        const float4* xp = (const float4*)&X[(size_t)(m0 + arow) * INDIM + k0 + ak];
        #pragma unroll
        for (int j = 0; j < 8; ++j) xa[j] = xp[j];
        const size_t bo = (size_t)(n0 + brow) * INDIM + k0 + bk;
        const float4* wp = (const float4*)&W[bo];
        const float4* cp = (const float4*)&C[bo];
        const float4* ip = (const float4*)&IC[bo];
        #pragma unroll
        for (int j = 0; j < 4; ++j) { wv[j] = wp[j]; cv[j] = cp[j]; iv[j] = ip[j]; }
    };

    auto stageT = [&]() {
        // ---- A: bf16(x), bf16(x^2)
        const float* xf = (const float*)xa;
        uint4* pa  = (uint4*)&As [arow * KSTR + ak];
        uint4* pa2 = (uint4*)&As2[arow * KSTR + ak];
        #pragma unroll
        for (int j = 0; j < 4; ++j) {
            const float* e = xf + j * 8;
            pa [j] = make_uint4(pkbf(e[0], e[1]), pkbf(e[2], e[3]),
                                pkbf(e[4], e[5]), pkbf(e[6], e[7]));
            pa2[j] = make_uint4(pkbf(e[0]*e[0], e[1]*e[1]), pkbf(e[2]*e[2], e[3]*e[3]),
                                pkbf(e[4]*e[4], e[5]*e[5]), pkbf(e[6]*e[6], e[7]*e[7]));
        }
        // ---- B: bf16(w), bf16(-2*c*s^2), bf16(s^2); fp32 cz partial
        const float* wf = (const float*)wv;
        const float* cf = (const float*)cv;
        const float* ff = (const float*)iv;
        const int bb = brow * KSTR + bk;
        uint4* pw = (uint4*)&Bw [bb];
        uint4* p1 = (uint4*)&Bg1[bb];
        uint4* p2 = (uint4*)&Bg2[bb];
        #pragma unroll
        for (int j = 0; j < 2; ++j) {
            float g1[8], g2[8];
            #pragma unroll
            for (int e = 0; e < 8; ++e) {
                const int idx = j * 8 + e;
                float s  = fminf(ff[idx], 1e8f);
                float qq = s * s;
                g2[e] = qq;
                g1[e] = -2.f * cf[idx] * qq;
                czp  = fmaf(cf[idx] * cf[idx], qq, czp);
            }
            const float* ww = wf + j * 8;
            pw[j] = make_uint4(pkbf(ww[0], ww[1]), pkbf(ww[2], ww[3]),
                               pkbf(ww[4], ww[5]), pkbf(ww[6], ww[7]));
            p1[j] = make_uint4(pkbf(g1[0], g1[1]), pkbf(g1[2], g1[3]),
                               pkbf(g1[4], g1[5]), pkbf(g1[6], g1[7]));
            p2[j] = make_uint4(pkbf(g2[0], g2[1]), pkbf(g2[2], g2[3]),
                               pkbf(g2[4], g2[5]), pkbf(g2[6], g2[7]));
        }
    };

    floatx4 zero = {0.f, 0.f, 0.f, 0.f};
    floatx4 accL[2] = {zero, zero};
    floatx4 accG[2] = {zero, zero};

    auto computeT = [&]() {
        #pragma unroll
        for (int kk = 0; kk < 4; ++kk) {
            const int ko = kk * 32 + q * 8;
            short8 a0 = *(const short8*)&As [(w * 16 + r) * KSTR + ko];
            short8 a2 = *(const short8*)&As2[(w * 16 + r) * KSTR + ko];
            #pragma unroll
            for (int nt = 0; nt < 2; ++nt) {
                const int br = (nt * 16 + r) * KSTR + ko;
                short8 bwf = *(const short8*)&Bw [br];
                short8 b1f = *(const short8*)&Bg1[br];
                short8 b2f = *(const short8*)&Bg2[br];
                accL[nt] = MFMA(a0, bwf, accL[nt], 0, 0, 0);
                accG[nt] = MFMA(a0, b1f, accG[nt], 0, 0, 0);
                accG[nt] = MFMA(a2, b2f, accG[nt], 0, 0, 0);
            }
        }
    };

    // ---- pipeline: 2 K-tiles, 4 barriers
    loadT(0);
    stageT();                 // tile 0 -> LDS
    loadT(TK);                // prefetch tile 1 (overlaps compute 0)
    __syncthreads();
    computeT();               // tile 0
    __syncthreads();
    stageT();                 // tile 1 -> LDS
    // cz reduce over the 8 threads sharing a B-row (consecutive lanes, intra-wave)
    czp += __shfl_down(czp, 4);
    czp += __shfl_down(czp, 2);
    czp += __shfl_down(czp, 1);
    if ((t & 7) == 0) sCz[brow] = czp;
    __syncthreads();
    computeT();               // tile 1

    // ---- epilogue straight from registers
    float* OutR = Out;
    float* OutG = Out + (size_t)BD * OUTD;
    #pragma unroll
    for (int nt = 0; nt < 2; ++nt) {
        const int n      = n0 + nt * 16 + r;
        const float bias = Bias[n];
        const float cz   = sCz[nt * 16 + r];
        #pragma unroll
        for (int reg = 0; reg < 4; ++reg) {
            const int m = m0 + w * 16 + q * 4 + reg;
            const float g   = expf(-(accG[nt][reg] + cz));
            const float res = (accL[nt][reg] + bias) * g;
            OutR[(size_t)m * OUTD + n] = res;
            OutG[(size_t)m * OUTD + n] = g;
        }
    }
}

extern "C" void kernel_launch(void* const* d_in, const int* in_sizes, int n_in,
                              void* d_out, int out_size, void* d_ws, size_t ws_size,
                              hipStream_t stream) {
    const float* X    = (const float*)d_in[0];
    const float* W    = (const float*)d_in[1];
    const float* Bias = (const float*)d_in[2];
    const float* C    = (const float*)d_in[3];
    const float* IC   = (const float*)d_in[4];
    float* Out = (float*)d_out;

    fgn_fused<<<512, 256, 0, stream>>>(X, W, Bias, C, IC, Out);
}

// Round 8
// 70.987 us; speedup vs baseline: 1.0281x; 1.0281x over previous
//
#include <hip/hip_runtime.h>
#include <hip/hip_bf16.h>
#include <math.h>

// FGN layer, single fused kernel, R8 — occupancy experiment:
//   res = (X @ W^T + bias) * g
//   g   = exp(-(sum_k x^2*s^2 - 2*x*c*s^2 + c^2*s^2)),  s = min(ic, 1e8)
// Block = 32m x 32n, 256 thr; each of 4 waves computes one 16x16 quadrant
// (3 MFMA streams: x*w, x*(-2cs^2), x^2*s^2). Grid 1024 = 4 blocks/CU
// = 4 waves/SIMD (R6 had 2) to hide cold-HBM staging latency — the pipes
// themselves were proven idle by R7 (cutting MFMA/barriers/LDS was neutral).
// LDS ~23 KB/block; cz = sum c^2 s^2 via fp32 partials + 8-lane shfl.

typedef __attribute__((ext_vector_type(8))) short short8;
typedef __attribute__((ext_vector_type(4))) float floatx4;

#define MFMA __builtin_amdgcn_mfma_f32_16x16x32_bf16
#define INDIM 256
#define OUTD  1024
#define BD    1024
#define TM 32
#define TN 32
#define TK 64
#define KSTR 72   // ushort stride (144 B: b128-aligned, <=2-way bank alias = free)

__device__ __forceinline__ unsigned pkbf(float a, float b) {
    union { __hip_bfloat162 h; unsigned u; } v;
    v.h = __float22bfloat162_rn(make_float2(a, b));
    return v.u;
}

__global__ __launch_bounds__(256)
void fgn_fused(const float* __restrict__ X, const float* __restrict__ W,
               const float* __restrict__ Bias, const float* __restrict__ C,
               const float* __restrict__ IC, float* __restrict__ Out)
{
    __shared__ __align__(16) unsigned short As [TM * KSTR];
    __shared__ __align__(16) unsigned short As2[TM * KSTR];
    __shared__ __align__(16) unsigned short Bw [TN * KSTR];
    __shared__ __align__(16) unsigned short Bg1[TN * KSTR];
    __shared__ __align__(16) unsigned short Bg2[TN * KSTR];
    __shared__ float sCz[TN];

    // XCD-aware swizzle: xcd = b%8 owns n-cols {xcd, xcd+8, xcd+16, xcd+24}
    const int b    = blockIdx.x;              // 0..1023
    const int xcd  = b & 7;
    const int n0   = (xcd + 8 * ((b >> 3) & 3)) * TN;
    const int m0   = (b >> 5) * TM;

    const int t    = threadIdx.x;
    const int w    = t >> 6;                  // wave id
    const int lane = t & 63;
    const int r    = lane & 15;
    const int q    = lane >> 4;
    const int mt   = w & 1;                   // wave's m-quadrant
    const int nt   = w >> 1;                  // wave's n-quadrant

    // staging coordinates: 32 rows, 8 k's (2 float4) per thread
    const int srow = t >> 3;                  // 0..31
    const int sk   = (t & 7) << 3;            // 0..56

    floatx4 zero = {0.f, 0.f, 0.f, 0.f};
    floatx4 accL = zero;
    floatx4 accG = zero;
    float czp = 0.f;

    for (int k0 = 0; k0 < INDIM; k0 += TK) {
        // ---- global loads (issued before the barrier: overlap prior compute)
        const float4* xp = (const float4*)&X[(size_t)(m0 + srow) * INDIM + k0 + sk];
        float4 x0 = xp[0], x1 = xp[1];
        const size_t bo = (size_t)(n0 + srow) * INDIM + k0 + sk;
        const float4* wp = (const float4*)&W[bo];
        const float4* cp = (const float4*)&C[bo];
        const float4* ip = (const float4*)&IC[bo];
        float4 w0 = wp[0], w1 = wp[1];
        float4 c0 = cp[0], c1 = cp[1];
        float4 i0 = ip[0], i1 = ip[1];

        __syncthreads();   // previous tile's compute done before LDS overwrite

        // ---- stage A: bf16(x), bf16(x^2)
        {
            float xf[8] = {x0.x,x0.y,x0.z,x0.w, x1.x,x1.y,x1.z,x1.w};
            uint4* pa  = (uint4*)&As [srow * KSTR + sk];
            uint4* pa2 = (uint4*)&As2[srow * KSTR + sk];
            pa[0]  = make_uint4(pkbf(xf[0],xf[1]), pkbf(xf[2],xf[3]),
                                pkbf(xf[4],xf[5]), pkbf(xf[6],xf[7]));
            pa2[0] = make_uint4(pkbf(xf[0]*xf[0],xf[1]*xf[1]), pkbf(xf[2]*xf[2],xf[3]*xf[3]),
                                pkbf(xf[4]*xf[4],xf[5]*xf[5]), pkbf(xf[6]*xf[6],xf[7]*xf[7]));
        }
        // ---- stage B: bf16(w), bf16(-2*c*s^2), bf16(s^2); fp32 cz partial
        {
            float wf[8] = {w0.x,w0.y,w0.z,w0.w, w1.x,w1.y,w1.z,w1.w};
            float cf[8] = {c0.x,c0.y,c0.z,c0.w, c1.x,c1.y,c1.z,c1.w};
            float ff[8] = {i0.x,i0.y,i0.z,i0.w, i1.x,i1.y,i1.z,i1.w};
            float g1[8], g2[8];
            #pragma unroll
            for (int e = 0; e < 8; ++e) {
                float s  = fminf(ff[e], 1e8f);
                float qq = s * s;
                g2[e] = qq;
                g1[e] = -2.f * cf[e] * qq;
                czp  = fmaf(cf[e] * cf[e], qq, czp);
            }
            const int bb = srow * KSTR + sk;
            *(uint4*)&Bw [bb] = make_uint4(pkbf(wf[0],wf[1]), pkbf(wf[2],wf[3]),
                                           pkbf(wf[4],wf[5]), pkbf(wf[6],wf[7]));
            *(uint4*)&Bg1[bb] = make_uint4(pkbf(g1[0],g1[1]), pkbf(g1[2],g1[3]),
                                           pkbf(g1[4],g1[5]), pkbf(g1[6],g1[7]));
            *(uint4*)&Bg2[bb] = make_uint4(pkbf(g2[0],g2[1]), pkbf(g2[2],g2[3]),
                                           pkbf(g2[4],g2[5]), pkbf(g2[6],g2[7]));
        }
        if (k0 + TK >= INDIM) {   // last tile: finalize cz before the barrier
            czp += __shfl_down(czp, 4);
            czp += __shfl_down(czp, 2);
            czp += __shfl_down(czp, 1);
            if ((t & 7) == 0) sCz[srow] = czp;
        }
        __syncthreads();

        // ---- compute: 2 k-steps of 32
        #pragma unroll
        for (int kk = 0; kk < 2; ++kk) {
            const int ko = kk * 32 + q * 8;
            short8 a0  = *(const short8*)&As [(mt * 16 + r) * KSTR + ko];
            short8 a2  = *(const short8*)&As2[(mt * 16 + r) * KSTR + ko];
            const int br = (nt * 16 + r) * KSTR + ko;
            short8 bwf = *(const short8*)&Bw [br];
            short8 b1f = *(const short8*)&Bg1[br];
            short8 b2f = *(const short8*)&Bg2[br];
            accL = MFMA(a0, bwf, accL, 0, 0, 0);
            accG = MFMA(a0, b1f, accG, 0, 0, 0);
            accG = MFMA(a2, b2f, accG, 0, 0, 0);
        }
    }

    // ---- epilogue straight from registers
    float* OutR = Out;
    float* OutG = Out + (size_t)BD * OUTD;
    const int n      = n0 + nt * 16 + r;
    const float bias = Bias[n];
    const float cz   = sCz[nt * 16 + r];
    #pragma unroll
    for (int reg = 0; reg < 4; ++reg) {
        const int m = m0 + mt * 16 + q * 4 + reg;
        const float g   = expf(-(accG[reg] + cz));
        const float res = (accL[reg] + bias) * g;
        OutR[(size_t)m * OUTD + n] = res;
        OutG[(size_t)m * OUTD + n] = g;
    }
}

extern "C" void kernel_launch(void* const* d_in, const int* in_sizes, int n_in,
                              void* d_out, int out_size, void* d_ws, size_t ws_size,
                              hipStream_t stream) {
    const float* X    = (const float*)d_in[0];
    const float* W    = (const float*)d_in[1];
    const float* Bias = (const float*)d_in[2];
    const float* C    = (const float*)d_in[3];
    const float* IC   = (const float*)d_in[4];
    float* Out = (float*)d_out;

    fgn_fused<<<1024, 256, 0, stream>>>(X, W, Bias, C, IC, Out);
}